// Round 19
// baseline (236.770 us; speedup 1.0000x reference)
//
#include <hip/hip_runtime.h>
#include <math.h>

#define N_NODES 100000
#define N_EDGES 1600000
#define LN_EPS 1e-5f
#define NBUK 782          // ceil(100000/128) buckets of 128 nodes
#define BCAP 2560         // bucket capacity (mean 2046, sd ~45; ~11 sigma)
#define BIN_TILE 8192     // edges per k_bin block (amortize per-block overhead)
#define BIN_BLOCKS ((N_EDGES + BIN_TILE - 1) / BIN_TILE)   // 196

using bf16x8 = __attribute__((ext_vector_type(8))) short;
using f32x4  = __attribute__((ext_vector_type(4))) float;
using f32x2  = __attribute__((ext_vector_type(2))) float;
using u32x4  = __attribute__((ext_vector_type(4))) unsigned;

__device__ __forceinline__ unsigned short f2bf(float f) {
    unsigned u = __float_as_uint(f);
    u += 0x7fffu + ((u >> 16) & 1u);            // round-to-nearest-even
    return (unsigned short)(u >> 16);
}
__device__ __forceinline__ float bflo(unsigned u) { return __uint_as_float(u << 16); }
__device__ __forceinline__ float bfhi(unsigned u) { return __uint_as_float(u & 0xffff0000u); }
__device__ __forceinline__ unsigned bfpack(float a, float b) {
    return (unsigned)f2bf(a) | ((unsigned)f2bf(b) << 16);
}

// ------- bucketed bin pass (LDS tile cache; single global read of src/dst) -------
__global__ __launch_bounds__(256) void k_bin(
    const int* __restrict__ src, const int* __restrict__ dst,
    int* __restrict__ gcur, unsigned* __restrict__ pairs) {
    int bid = blockIdx.x;
    int t = threadIdx.x;
    __shared__ unsigned wbuf[BIN_TILE];          // packed (d&127)<<25 | src
    __shared__ unsigned short bbuf[BIN_TILE];    // bucket id d>>7
    __shared__ int bcnt[NBUK];
    __shared__ int bbase[NBUK];
    for (int i = t; i < NBUK; i += 256) bcnt[i] = 0;
    __syncthreads();
    int e0 = bid * BIN_TILE;
    int n = N_EDGES - e0; if (n > BIN_TILE) n = BIN_TILE;
    for (int i = t; i < n; i += 256) {
        int d = __builtin_nontemporal_load(&dst[e0 + i]);
        int s = __builtin_nontemporal_load(&src[e0 + i]);
        wbuf[i] = ((unsigned)(d & 127) << 25) | (unsigned)s;
        bbuf[i] = (unsigned short)(d >> 7);
        atomicAdd(&bcnt[d >> 7], 1);
    }
    __syncthreads();
    for (int i = t; i < NBUK; i += 256) {
        int c = bcnt[i];
        bbase[i] = (c > 0) ? atomicAdd(&gcur[i], c) : 0;
        bcnt[i] = 0;
    }
    __syncthreads();
    for (int i = t; i < n; i += 256) {
        int b = bbuf[i];
        int idx = bbase[b] + atomicAdd(&bcnt[b], 1);
        if (idx < BCAP)
            pairs[(size_t)b * BCAP + idx] = wbuf[i];
    }
}

// per-bucket local CSR (computes own prefix base); blocks >= NBUK pack B fragments:
// Bp[((n*KSTEPS+ks)*64 + lane)*8 + j] = bf16(W[ks*32+(lane>>4)*8+j][n*16+(lane&15)])
__global__ __launch_bounds__(256) void k_csr(
    const unsigned* __restrict__ pairs, const int* __restrict__ gcur,
    int* __restrict__ rowptr, float* __restrict__ dinv, int* __restrict__ col,
    const float* __restrict__ W1, const float* __restrict__ W2,
    const float* __restrict__ Wm1, short* __restrict__ Bp1,
    short* __restrict__ Bp2, short* __restrict__ Bpm) {
    int b = blockIdx.x;
    int t = threadIdx.x;
    if (b >= NBUK) {                             // weight-pack blocks
        int cid = (b - NBUK) * 256 + t;          // chunk id, 8 bf16 per chunk
        if (cid >= 8192) return;
        const float* Wsrc; short* Bdst; int KST; int c;
        if (cid < 2048)      { Wsrc = W1;  Bdst = Bp1; KST = 4; c = cid; }
        else if (cid < 4096) { Wsrc = W2;  Bdst = Bp2; KST = 4; c = cid - 2048; }
        else                 { Wsrc = Wm1; Bdst = Bpm; KST = 8; c = cid - 4096; }
        int nks = c >> 6, lane = c & 63;
        int n = nks / KST, ks = nks % KST;
        int quad = lane >> 4, fr = lane & 15;
        int col0 = n * 16 + fr;
        int krow = ks * 32 + quad * 8;
        union { short s[8]; u32x4 q; } v;
#pragma unroll
        for (int j = 0; j < 8; ++j)
            v.s[j] = (short)f2bf(Wsrc[(size_t)(krow + j) * 128 + col0]);
        *(u32x4*)(Bdst + (size_t)c * 8) = v.q;
        return;
    }
    int lane = t & 63, wid = t >> 6;
    __shared__ int redsum[4];
    int part = 0;
    for (int i = t; i < b; i += 256) part += gcur[i];
#pragma unroll
    for (int o = 32; o; o >>= 1) part += __shfl_xor(part, o);
    if (lane == 0) redsum[wid] = part;
    __syncthreads();
    int base = redsum[0] + redsum[1] + redsum[2] + redsum[3];
    if (b == 0 && t == 0) rowptr[N_NODES] = N_EDGES;

    int lo = b << 7;
    int nloc = N_NODES - lo; if (nloc > 128) nloc = 128;
    int size = gcur[b]; if (size > BCAP) size = BCAP;
    __shared__ int lcnt[128], lofs[128], lcur[128];
    if (t < 128) lcnt[t] = 0;
    __syncthreads();
    const unsigned* bp = pairs + (size_t)b * BCAP;
    for (int i = t; i < size; i += 256) atomicAdd(&lcnt[bp[i] >> 25], 1);
    __syncthreads();
    if (t < 128) lofs[t] = lcnt[t];
    __syncthreads();
    for (int o = 1; o < 128; o <<= 1) {
        int v = 0;
        if (t < 128 && t >= o) v = lofs[t - o];
        __syncthreads();
        if (t < 128) lofs[t] += v;
        __syncthreads();
    }
    if (t < 128) {
        int ex = lofs[t] - lcnt[t];               // exclusive
        if (t < nloc) {
            rowptr[lo + t] = base + ex;
            dinv[lo + t] = rsqrtf((float)(lcnt[t] + 1));
        }
        lcur[t] = ex;
    }
    __syncthreads();
    for (int i = t; i < size; i += 256) {
        unsigned w = bp[i];
        int pos = atomicAdd(&lcur[w >> 25], 1);
        col[base + pos] = (int)(w & 0x1FFFFFFu);
    }
}

// --- coalesced fp8 C-store: stage bf16 tile in LDS, convert on readback ---
__device__ __forceinline__ void store_tile_fp8(
    unsigned* wtile, int quad, int fr, int lane, int row0w,
    const f32x4* acc, const float* scale4, unsigned* C8) {
    unsigned short* w16 = (unsigned short*)wtile;
#pragma unroll
    for (int j = 0; j < 4; ++j) {
        float s = scale4[j];
#pragma unroll
        for (int n = 0; n < 8; ++n)
            w16[(quad * 4 + j) * 132 + n * 16 + fr] = f2bf(acc[n][j] * s);
    }
    __builtin_amdgcn_s_waitcnt(0);               // drain lgkm before cross-lane read
    int lrow = lane >> 2, chk = lane & 3;
    int gr = row0w + lrow;
    if (gr < N_NODES) {
#pragma unroll
        for (int q = 0; q < 4; ++q) {
            u32x4 v = *(u32x4*)&wtile[lrow * 66 + chk * 16 + q * 4];
            int d0 = __builtin_amdgcn_cvt_pk_fp8_f32(bflo(v[0]), bfhi(v[0]), 0, false);
            d0 = __builtin_amdgcn_cvt_pk_fp8_f32(bflo(v[1]), bfhi(v[1]), d0, true);
            int d1 = __builtin_amdgcn_cvt_pk_fp8_f32(bflo(v[2]), bfhi(v[2]), 0, false);
            d1 = __builtin_amdgcn_cvt_pk_fp8_f32(bflo(v[3]), bfhi(v[3]), d1, true);
            uint2 dd = make_uint2((unsigned)d0, (unsigned)d1);
            *(uint2*)(C8 + (size_t)gr * 32 + chk * 8 + q * 2) = dd;
        }
    }
}

// ------------- GEMM1: hs1 = fp8((x@W1)*dinv), also emits xb = bf16(x) -------------
__global__ __launch_bounds__(256) void k_gemm_x(
    const float* __restrict__ x, const short* __restrict__ Bp1,
    const float* __restrict__ dinv, unsigned* __restrict__ xbu,
    unsigned* __restrict__ hs1u8) {
    __shared__ unsigned ctile[4][16 * 66];
    int t = threadIdx.x;
    int wave = t >> 6, lane = t & 63;
    int quad = lane >> 4, fr = lane & 15;
    int row0 = blockIdx.x * 64 + wave * 16;
    int arow = row0 + fr;
    if (arow >= N_NODES) arow = N_NODES - 1;

    f32x4 acc[8];
#pragma unroll
    for (int n = 0; n < 8; ++n) acc[n] = (f32x4){0.f, 0.f, 0.f, 0.f};

#pragma unroll
    for (int ks = 0; ks < 4; ++ks) {
        int kof = ks * 32 + quad * 8;            // shorts
        const f32x4* xr = (const f32x4*)(x + (size_t)arow * 128 + kof);
        f32x4 v0 = __builtin_nontemporal_load(&xr[0]);
        f32x4 v1 = __builtin_nontemporal_load(&xr[1]);
        union { unsigned u[4]; bf16x8 v; u32x4 q; } cv;
        cv.u[0] = bfpack(v0[0], v0[1]);
        cv.u[1] = bfpack(v0[2], v0[3]);
        cv.u[2] = bfpack(v1[0], v1[1]);
        cv.u[3] = bfpack(v1[2], v1[3]);
        *(u32x4*)(xbu + (size_t)arow * 64 + ks * 16 + quad * 4) = cv.q;
#pragma unroll
        for (int n = 0; n < 8; ++n) {
            bf16x8 b = *(const bf16x8*)(Bp1 + ((size_t)(n * 4 + ks) * 64 + lane) * 8);
            acc[n] = __builtin_amdgcn_mfma_f32_16x16x32_bf16(cv.v, b, acc[n], 0, 0, 0);
        }
    }
    float sc[4];
#pragma unroll
    for (int j = 0; j < 4; ++j) {
        int r = row0 + quad * 4 + j;
        sc[j] = dinv[r < N_NODES ? r : N_NODES - 1];
    }
    store_tile_fp8(ctile[wave], quad, fr, lane, row0, acc, sc, hs1u8);
}

// ------------- bf16 MFMA GEMM: LDS-staged A + fragment-packed B -------------
// MODE 0: epilogue *dinv[row], fp8 C via LDS tile.
// MODE 1: A=concat(A0,A1) (K=256); epilogue relu(.+bias) @ Wm2 + bm2 -> out[N,2]
template <int MODE, int KSTEPS>
__global__ __launch_bounds__(256) void k_gemm_mfma(
    const short* __restrict__ A0, const short* __restrict__ A1,
    const short* __restrict__ Bp, const float* __restrict__ dinv,
    const float* __restrict__ bias, unsigned* __restrict__ C8,
    const float* __restrict__ Wm2, const float* __restrict__ bm2,
    float* __restrict__ out) {
    constexpr int K = KSTEPS * 32;               // 128 or 256
    constexpr int CHUNKS = K / 8;                // 16B chunks per row
    __shared__ short atile[64 * K];
    __shared__ unsigned ctile[MODE == 0 ? 4 * 16 * 66 : 4];
    int t = threadIdx.x;
    int wave = t >> 6, lane = t & 63;
    int quad = lane >> 4, fr = lane & 15;
    int row0 = blockIdx.x * 64 + wave * 16;

    // ---- stage A tile (64 rows x K) into swizzled LDS ----
#pragma unroll
    for (int i = 0; i < (64 * CHUNKS) / 256; ++i) {
        int idx = i * 256 + t;
        int r = idx / CHUNKS;
        int c = idx % CHUNKS;
        int grow = blockIdx.x * 64 + r;
        if (grow >= N_NODES) grow = N_NODES - 1;
        const short* srcp;
        if (MODE == 1 && c >= 16) srcp = A1 + (size_t)grow * 128 + (c - 16) * 8;
        else                      srcp = A0 + (size_t)grow * 128 + c * 8;
        u32x4 v = *(const u32x4*)srcp;
        *(u32x4*)&atile[r * K + (c ^ (r & 7)) * 8] = v;
    }
    __syncthreads();

    f32x4 acc[8];
#pragma unroll
    for (int n = 0; n < 8; ++n) acc[n] = (f32x4){0.f, 0.f, 0.f, 0.f};

    int lrow = wave * 16 + fr;
#pragma unroll
    for (int ks = 0; ks < KSTEPS; ++ks) {
        int kc = ks * 4 + quad;
        bf16x8 a = *(const bf16x8*)&atile[lrow * K + (kc ^ (lrow & 7)) * 8];
#pragma unroll
        for (int n = 0; n < 8; ++n) {
            bf16x8 b = *(const bf16x8*)(Bp + ((size_t)(n * KSTEPS + ks) * 64 + lane) * 8);
            acc[n] = __builtin_amdgcn_mfma_f32_16x16x32_bf16(a, b, acc[n], 0, 0, 0);
        }
    }

    if (MODE == 0) {
        float sc[4];
#pragma unroll
        for (int j = 0; j < 4; ++j) {
            int r = row0 + quad * 4 + j;
            sc[j] = dinv[r < N_NODES ? r : N_NODES - 1];
        }
        store_tile_fp8(ctile + wave * 16 * 66, quad, fr, lane, row0, acc, sc, C8);
    } else {
        int r0 = row0 + quad * 4;
        float pr0[4] = {0.f, 0.f, 0.f, 0.f};
        float pr1[4] = {0.f, 0.f, 0.f, 0.f};
#pragma unroll
        for (int n = 0; n < 8; ++n) {
            int c = n * 16 + fr;
            float bsn = bias[c];
            float2 w = ((const float2*)Wm2)[c];
#pragma unroll
            for (int j = 0; j < 4; ++j) {
                float y = acc[n][j] + bsn;
                y = y > 0.f ? y : 0.f;
                pr0[j] = fmaf(y, w.x, pr0[j]);
                pr1[j] = fmaf(y, w.y, pr1[j]);
            }
        }
#pragma unroll
        for (int o = 1; o < 16; o <<= 1) {
#pragma unroll
            for (int j = 0; j < 4; ++j) {
                pr0[j] += __shfl_xor(pr0[j], o);
                pr1[j] += __shfl_xor(pr1[j], o);
            }
        }
        if (fr == 0) {
            float c0 = bm2[0], c1 = bm2[1];
#pragma unroll
            for (int j = 0; j < 4; ++j) {
                int r = r0 + j;
                if (r < N_NODES) {
                    out[(size_t)r * 2 + 0] = pr0[j] + c0;
                    out[(size_t)r * 2 + 1] = pr1[j] + c1;
                }
            }
        }
    }
}

// ------- fused pull-aggregate + bias + LayerNorm + ReLU (wave per node) -------
// hs8: [N][128] fp8 e4m3 rows (pre-scaled by dinv[src]); lane reads 2 ch (ushort).
__global__ __launch_bounds__(256) void k_agg(
    const unsigned short* __restrict__ hs8, const int* __restrict__ rowptr,
    const int* __restrict__ col, const float* __restrict__ dinv,
    const float* __restrict__ b, const float* __restrict__ g,
    const float* __restrict__ be, unsigned* __restrict__ out) {
    int wv = blockIdx.x * 4 + (threadIdx.x >> 6);
    int lane = threadIdx.x & 63;
    if (wv >= N_NODES) return;
    int p0 = rowptr[wv], p1 = rowptr[wv + 1];
    f32x2 sv = __builtin_amdgcn_cvt_pk_f32_fp8(hs8[(size_t)wv * 64 + lane], false);
    float ax = sv[0], ay = sv[1];                   // self-loop term
    int ne = p1 - p0;
    for (int base = 0; base < ne; base += 64) {
        int rem = ne - base;
        if (rem > 64) rem = 64;
        int myc = (lane < rem) ? col[p0 + base + lane] : 0;
        int j = 0;
        for (; j + 8 <= rem; j += 8) {
            int s0 = __shfl(myc, j);
            int s1 = __shfl(myc, j + 1);
            int s2 = __shfl(myc, j + 2);
            int s3 = __shfl(myc, j + 3);
            int s4 = __shfl(myc, j + 4);
            int s5 = __shfl(myc, j + 5);
            int s6 = __shfl(myc, j + 6);
            int s7 = __shfl(myc, j + 7);
            unsigned u0 = hs8[(size_t)s0 * 64 + lane];
            unsigned u1 = hs8[(size_t)s1 * 64 + lane];
            unsigned u2 = hs8[(size_t)s2 * 64 + lane];
            unsigned u3 = hs8[(size_t)s3 * 64 + lane];
            unsigned u4 = hs8[(size_t)s4 * 64 + lane];
            unsigned u5 = hs8[(size_t)s5 * 64 + lane];
            unsigned u6 = hs8[(size_t)s6 * 64 + lane];
            unsigned u7 = hs8[(size_t)s7 * 64 + lane];
            f32x2 v0 = __builtin_amdgcn_cvt_pk_f32_fp8(u0, false);
            f32x2 v1 = __builtin_amdgcn_cvt_pk_f32_fp8(u1, false);
            f32x2 v2 = __builtin_amdgcn_cvt_pk_f32_fp8(u2, false);
            f32x2 v3 = __builtin_amdgcn_cvt_pk_f32_fp8(u3, false);
            f32x2 v4 = __builtin_amdgcn_cvt_pk_f32_fp8(u4, false);
            f32x2 v5 = __builtin_amdgcn_cvt_pk_f32_fp8(u5, false);
            f32x2 v6 = __builtin_amdgcn_cvt_pk_f32_fp8(u6, false);
            f32x2 v7 = __builtin_amdgcn_cvt_pk_f32_fp8(u7, false);
            ax += v0[0] + v1[0] + v2[0] + v3[0] + v4[0] + v5[0] + v6[0] + v7[0];
            ay += v0[1] + v1[1] + v2[1] + v3[1] + v4[1] + v5[1] + v6[1] + v7[1];
        }
        for (; j + 4 <= rem; j += 4) {
            int s0 = __shfl(myc, j);
            int s1 = __shfl(myc, j + 1);
            int s2 = __shfl(myc, j + 2);
            int s3 = __shfl(myc, j + 3);
            f32x2 v0 = __builtin_amdgcn_cvt_pk_f32_fp8(hs8[(size_t)s0 * 64 + lane], false);
            f32x2 v1 = __builtin_amdgcn_cvt_pk_f32_fp8(hs8[(size_t)s1 * 64 + lane], false);
            f32x2 v2 = __builtin_amdgcn_cvt_pk_f32_fp8(hs8[(size_t)s2 * 64 + lane], false);
            f32x2 v3 = __builtin_amdgcn_cvt_pk_f32_fp8(hs8[(size_t)s3 * 64 + lane], false);
            ax += v0[0] + v1[0] + v2[0] + v3[0];
            ay += v0[1] + v1[1] + v2[1] + v3[1];
        }
        for (; j < rem; ++j) {
            f32x2 v0 = __builtin_amdgcn_cvt_pk_f32_fp8(
                hs8[(size_t)__shfl(myc, j) * 64 + lane], false);
            ax += v0[0];
            ay += v0[1];
        }
    }
    float dv = dinv[wv];
    float t0 = ax * dv + b[2 * lane];
    float t1 = ay * dv + b[2 * lane + 1];
    float ssum = t0 + t1;
#pragma unroll
    for (int o = 32; o; o >>= 1) ssum += __shfl_xor(ssum, o);
    float mu = ssum * (1.0f / 128.0f);
    float d0 = t0 - mu, d1 = t1 - mu;
    float vs = d0 * d0 + d1 * d1;
#pragma unroll
    for (int o = 32; o; o >>= 1) vs += __shfl_xor(vs, o);
    float rstd = rsqrtf(vs * (1.0f / 128.0f) + LN_EPS);
    float y0 = d0 * rstd * g[2 * lane] + be[2 * lane];
    float y1 = d1 * rstd * g[2 * lane + 1] + be[2 * lane + 1];
    y0 = y0 > 0.f ? y0 : 0.f;
    y1 = y1 > 0.f ? y1 : 0.f;
    out[(size_t)wv * 64 + lane] = bfpack(y0, y1);
}

extern "C" void kernel_launch(void* const* d_in, const int* in_sizes, int n_in,
                              void* d_out, int out_size, void* d_ws, size_t ws_size,
                              hipStream_t stream) {
    (void)in_sizes; (void)n_in; (void)out_size; (void)ws_size;
    const float* x   = (const float*)d_in[0];
    const int*   ei  = (const int*)d_in[1];
    const float* W1  = (const float*)d_in[2];
    const float* b1  = (const float*)d_in[3];
    const float* g1  = (const float*)d_in[4];
    const float* be1 = (const float*)d_in[5];
    const float* W2  = (const float*)d_in[6];
    const float* b2  = (const float*)d_in[7];
    const float* g2  = (const float*)d_in[8];
    const float* be2 = (const float*)d_in[9];
    const float* Wm1 = (const float*)d_in[10];
    const float* bm1 = (const float*)d_in[11];
    const float* Wm2 = (const float*)d_in[12];
    const float* bm2 = (const float*)d_in[13];
    const int* srcI = ei;
    const int* dstI = ei + N_EDGES;
    float* out = (float*)d_out;

    char* ws = (char*)d_ws;
    size_t off = 0;
    auto alloc = [&](size_t bytes) -> char* {
        char* p = ws + off;
        off += (bytes + 255) & ~(size_t)255;
        return p;
    };
    short* xb      = (short*)alloc((size_t)N_NODES * 128 * 2);  // x in bf16
    unsigned* bufS = (unsigned*)alloc((size_t)N_NODES * 128);   // hs1/hs2 fp8 rows
    short* bufH    = (short*)alloc((size_t)N_NODES * 128 * 2);  // h1n/h2n bf16
    short* Bp1     = (short*)alloc(128 * 128 * 2);              // fragment-packed B
    short* Bp2     = (short*)alloc(128 * 128 * 2);
    short* Bpm     = (short*)alloc(256 * 128 * 2);
    int* rowptr    = (int*)alloc((size_t)(N_NODES + 1) * 4);
    int* col       = (int*)alloc((size_t)N_EDGES * 4);
    unsigned* pairs = (unsigned*)alloc((size_t)NBUK * BCAP * 4);
    int* gcur      = (int*)alloc(NBUK * 4);
    float* dinv    = (float*)alloc((size_t)N_NODES * 4);

    hipMemsetAsync(gcur, 0, NBUK * 4, stream);

    // bucketed CSR; weight fragment-packing rides on k_csr's grid
    k_bin<<<BIN_BLOCKS, 256, 0, stream>>>(srcI, dstI, gcur, pairs);
    k_csr<<<NBUK + 32, 256, 0, stream>>>(pairs, gcur, rowptr, dinv, col,
                                         W1, W2, Wm1, Bp1, Bp2, Bpm);

    int gb = (N_NODES + 63) / 64;
    int ab = (N_NODES + 3) / 4;
    // layer 1 (x convert fused into GEMM1)
    k_gemm_x<<<gb, 256, 0, stream>>>(x, Bp1, dinv, (unsigned*)xb, bufS);
    k_agg<<<ab, 256, 0, stream>>>((unsigned short*)bufS, rowptr, col, dinv,
                                  b1, g1, be1, (unsigned*)bufH);
    // layer 2
    k_gemm_mfma<0, 4><<<gb, 256, 0, stream>>>(bufH, nullptr, Bp2, dinv, nullptr,
                                              bufS, nullptr, nullptr, nullptr);
    k_agg<<<ab, 256, 0, stream>>>((unsigned short*)bufS, rowptr, col, dinv,
                                  b2, g2, be2, (unsigned*)bufH);
    // fused MLP (hidden GEMM + relu + final 128x2 + bias)
    k_gemm_mfma<1, 8><<<gb, 256, 0, stream>>>(bufH, xb, Bpm, nullptr, bm1, nullptr,
                                              Wm2, bm2, out);
}

// Round 20
// 227.536 us; speedup vs baseline: 1.0406x; 1.0406x over previous
//
#include <hip/hip_runtime.h>
#include <math.h>

#define N_NODES 100000
#define N_EDGES 1600000
#define LN_EPS 1e-5f
#define NBUK 782          // ceil(100000/128) buckets of 128 nodes
#define BCAP 2560         // bucket capacity (mean 2046, sd ~45; ~11 sigma)
#define BIN_TILE 4096     // edges per k_bin block
#define BIN_BLOCKS ((N_EDGES + BIN_TILE - 1) / BIN_TILE)   // 391

using bf16x8 = __attribute__((ext_vector_type(8))) short;
using f32x4  = __attribute__((ext_vector_type(4))) float;
using f32x2  = __attribute__((ext_vector_type(2))) float;
using u32x4  = __attribute__((ext_vector_type(4))) unsigned;

__device__ __forceinline__ unsigned short f2bf(float f) {
    unsigned u = __float_as_uint(f);
    u += 0x7fffu + ((u >> 16) & 1u);            // round-to-nearest-even
    return (unsigned short)(u >> 16);
}
__device__ __forceinline__ float bflo(unsigned u) { return __uint_as_float(u << 16); }
__device__ __forceinline__ float bfhi(unsigned u) { return __uint_as_float(u & 0xffff0000u); }
__device__ __forceinline__ unsigned bfpack(float a, float b) {
    return (unsigned)f2bf(a) | ((unsigned)f2bf(b) << 16);
}

// ------- bucketed bin pass (LDS tile cache); extra blocks fragment-pack B -------
// Bp[((n*KSTEPS+ks)*64 + lane)*8 + j] = bf16(W[ks*32+(lane>>4)*8+j][n*16+(lane&15)])
__global__ __launch_bounds__(256) void k_bin(
    const int* __restrict__ src, const int* __restrict__ dst,
    int* __restrict__ gcur, unsigned* __restrict__ pairs,
    const float* __restrict__ W1, const float* __restrict__ W2,
    const float* __restrict__ Wm1, short* __restrict__ Bp1,
    short* __restrict__ Bp2, short* __restrict__ Bpm) {
    int bid = blockIdx.x;
    int t = threadIdx.x;
    if (bid >= BIN_BLOCKS) {                     // weight-pack blocks
        int cid = (bid - BIN_BLOCKS) * 256 + t;  // chunk id, 8 bf16 per chunk
        if (cid >= 8192) return;
        const float* Wsrc; short* Bdst; int KST; int c;
        if (cid < 2048)      { Wsrc = W1;  Bdst = Bp1; KST = 4; c = cid; }
        else if (cid < 4096) { Wsrc = W2;  Bdst = Bp2; KST = 4; c = cid - 2048; }
        else                 { Wsrc = Wm1; Bdst = Bpm; KST = 8; c = cid - 4096; }
        int nks = c >> 6, lane = c & 63;
        int n = nks / KST, ks = nks % KST;
        int quad = lane >> 4, fr = lane & 15;
        int col0 = n * 16 + fr;
        int krow = ks * 32 + quad * 8;
        union { short s[8]; u32x4 q; } v;
#pragma unroll
        for (int j = 0; j < 8; ++j)
            v.s[j] = (short)f2bf(Wsrc[(size_t)(krow + j) * 128 + col0]);
        *(u32x4*)(Bdst + (size_t)c * 8) = v.q;
        return;
    }
    __shared__ unsigned wbuf[BIN_TILE];          // packed (d&127)<<25 | src
    __shared__ unsigned short bbuf[BIN_TILE];    // bucket id d>>7
    __shared__ int bcnt[NBUK];
    __shared__ int bbase[NBUK];
    for (int i = t; i < NBUK; i += 256) bcnt[i] = 0;
    __syncthreads();
    int e0 = bid * BIN_TILE;
    int n = N_EDGES - e0; if (n > BIN_TILE) n = BIN_TILE;
    for (int i = t; i < n; i += 256) {
        int d = __builtin_nontemporal_load(&dst[e0 + i]);
        int s = __builtin_nontemporal_load(&src[e0 + i]);
        wbuf[i] = ((unsigned)(d & 127) << 25) | (unsigned)s;
        bbuf[i] = (unsigned short)(d >> 7);
        atomicAdd(&bcnt[d >> 7], 1);
    }
    __syncthreads();
    for (int i = t; i < NBUK; i += 256) {
        int c = bcnt[i];
        bbase[i] = (c > 0) ? atomicAdd(&gcur[i], c) : 0;
        bcnt[i] = 0;
    }
    __syncthreads();
    for (int i = t; i < n; i += 256) {
        int b = bbuf[i];
        int idx = bbase[b] + atomicAdd(&bcnt[b], 1);
        if (idx < BCAP)
            pairs[(size_t)b * BCAP + idx] = wbuf[i];
    }
}

// per-bucket local CSR (computes own prefix base)
__global__ __launch_bounds__(256) void k_csr(
    const unsigned* __restrict__ pairs, const int* __restrict__ gcur,
    int* __restrict__ rowptr, float* __restrict__ dinv, int* __restrict__ col) {
    int b = blockIdx.x;
    int t = threadIdx.x;
    int lane = t & 63, wid = t >> 6;
    __shared__ int redsum[4];
    int part = 0;
    for (int i = t; i < b; i += 256) part += gcur[i];
#pragma unroll
    for (int o = 32; o; o >>= 1) part += __shfl_xor(part, o);
    if (lane == 0) redsum[wid] = part;
    __syncthreads();
    int base = redsum[0] + redsum[1] + redsum[2] + redsum[3];
    if (b == 0 && t == 0) rowptr[N_NODES] = N_EDGES;

    int lo = b << 7;
    int nloc = N_NODES - lo; if (nloc > 128) nloc = 128;
    int size = gcur[b]; if (size > BCAP) size = BCAP;
    __shared__ int lcnt[128], lofs[128], lcur[128];
    if (t < 128) lcnt[t] = 0;
    __syncthreads();
    const unsigned* bp = pairs + (size_t)b * BCAP;
    for (int i = t; i < size; i += 256) atomicAdd(&lcnt[bp[i] >> 25], 1);
    __syncthreads();
    if (t < 128) lofs[t] = lcnt[t];
    __syncthreads();
    for (int o = 1; o < 128; o <<= 1) {
        int v = 0;
        if (t < 128 && t >= o) v = lofs[t - o];
        __syncthreads();
        if (t < 128) lofs[t] += v;
        __syncthreads();
    }
    if (t < 128) {
        int ex = lofs[t] - lcnt[t];               // exclusive
        if (t < nloc) {
            rowptr[lo + t] = base + ex;
            dinv[lo + t] = rsqrtf((float)(lcnt[t] + 1));
        }
        lcur[t] = ex;
    }
    __syncthreads();
    for (int i = t; i < size; i += 256) {
        unsigned w = bp[i];
        int pos = atomicAdd(&lcur[w >> 25], 1);
        col[base + pos] = (int)(w & 0x1FFFFFFu);
    }
}

// --- coalesced fp8 C-store: stage bf16 tile in LDS, convert on readback ---
__device__ __forceinline__ void store_tile_fp8(
    unsigned* wtile, int quad, int fr, int lane, int row0w,
    const f32x4* acc, const float* scale4, unsigned* C8) {
    unsigned short* w16 = (unsigned short*)wtile;
#pragma unroll
    for (int j = 0; j < 4; ++j) {
        float s = scale4[j];
#pragma unroll
        for (int n = 0; n < 8; ++n)
            w16[(quad * 4 + j) * 132 + n * 16 + fr] = f2bf(acc[n][j] * s);
    }
    __builtin_amdgcn_s_waitcnt(0);               // drain lgkm before cross-lane read
    int lrow = lane >> 2, chk = lane & 3;
    int gr = row0w + lrow;
    if (gr < N_NODES) {
#pragma unroll
        for (int q = 0; q < 4; ++q) {
            u32x4 v = *(u32x4*)&wtile[lrow * 66 + chk * 16 + q * 4];
            int d0 = __builtin_amdgcn_cvt_pk_fp8_f32(bflo(v[0]), bfhi(v[0]), 0, false);
            d0 = __builtin_amdgcn_cvt_pk_fp8_f32(bflo(v[1]), bfhi(v[1]), d0, true);
            int d1 = __builtin_amdgcn_cvt_pk_fp8_f32(bflo(v[2]), bfhi(v[2]), 0, false);
            d1 = __builtin_amdgcn_cvt_pk_fp8_f32(bflo(v[3]), bfhi(v[3]), d1, true);
            uint2 dd = make_uint2((unsigned)d0, (unsigned)d1);
            *(uint2*)(C8 + (size_t)gr * 32 + chk * 8 + q * 2) = dd;
        }
    }
}

// ------------- GEMM1: hs1 = fp8((x@W1)*dinv), also emits xb = bf16(x) -------------
__global__ __launch_bounds__(256) void k_gemm_x(
    const float* __restrict__ x, const short* __restrict__ Bp1,
    const float* __restrict__ dinv, unsigned* __restrict__ xbu,
    unsigned* __restrict__ hs1u8) {
    __shared__ unsigned ctile[4][16 * 66];
    int t = threadIdx.x;
    int wave = t >> 6, lane = t & 63;
    int quad = lane >> 4, fr = lane & 15;
    int row0 = blockIdx.x * 64 + wave * 16;
    int arow = row0 + fr;
    if (arow >= N_NODES) arow = N_NODES - 1;

    f32x4 acc[8];
#pragma unroll
    for (int n = 0; n < 8; ++n) acc[n] = (f32x4){0.f, 0.f, 0.f, 0.f};

#pragma unroll
    for (int ks = 0; ks < 4; ++ks) {
        int kof = ks * 32 + quad * 8;            // shorts
        const f32x4* xr = (const f32x4*)(x + (size_t)arow * 128 + kof);
        f32x4 v0 = __builtin_nontemporal_load(&xr[0]);
        f32x4 v1 = __builtin_nontemporal_load(&xr[1]);
        union { unsigned u[4]; bf16x8 v; u32x4 q; } cv;
        cv.u[0] = bfpack(v0[0], v0[1]);
        cv.u[1] = bfpack(v0[2], v0[3]);
        cv.u[2] = bfpack(v1[0], v1[1]);
        cv.u[3] = bfpack(v1[2], v1[3]);
        *(u32x4*)(xbu + (size_t)arow * 64 + ks * 16 + quad * 4) = cv.q;
#pragma unroll
        for (int n = 0; n < 8; ++n) {
            bf16x8 b = *(const bf16x8*)(Bp1 + ((size_t)(n * 4 + ks) * 64 + lane) * 8);
            acc[n] = __builtin_amdgcn_mfma_f32_16x16x32_bf16(cv.v, b, acc[n], 0, 0, 0);
        }
    }
    float sc[4];
#pragma unroll
    for (int j = 0; j < 4; ++j) {
        int r = row0 + quad * 4 + j;
        sc[j] = dinv[r < N_NODES ? r : N_NODES - 1];
    }
    store_tile_fp8(ctile[wave], quad, fr, lane, row0, acc, sc, hs1u8);
}

// ------------- bf16 MFMA GEMM: LDS-staged A + fragment-packed B -------------
// MODE 0: epilogue *dinv[row], fp8 C via LDS tile.
// MODE 1: A=concat(A0,A1) (K=256); epilogue relu(.+bias) @ Wm2 + bm2 -> out[N,2]
template <int MODE, int KSTEPS>
__global__ __launch_bounds__(256) void k_gemm_mfma(
    const short* __restrict__ A0, const short* __restrict__ A1,
    const short* __restrict__ Bp, const float* __restrict__ dinv,
    const float* __restrict__ bias, unsigned* __restrict__ C8,
    const float* __restrict__ Wm2, const float* __restrict__ bm2,
    float* __restrict__ out) {
    constexpr int K = KSTEPS * 32;               // 128 or 256
    constexpr int CHUNKS = K / 8;                // 16B chunks per row
    __shared__ short atile[64 * K];
    __shared__ unsigned ctile[MODE == 0 ? 4 * 16 * 66 : 4];
    int t = threadIdx.x;
    int wave = t >> 6, lane = t & 63;
    int quad = lane >> 4, fr = lane & 15;
    int row0 = blockIdx.x * 64 + wave * 16;

    // ---- stage A tile (64 rows x K) into swizzled LDS ----
#pragma unroll
    for (int i = 0; i < (64 * CHUNKS) / 256; ++i) {
        int idx = i * 256 + t;
        int r = idx / CHUNKS;
        int c = idx % CHUNKS;
        int grow = blockIdx.x * 64 + r;
        if (grow >= N_NODES) grow = N_NODES - 1;
        const short* srcp;
        if (MODE == 1 && c >= 16) srcp = A1 + (size_t)grow * 128 + (c - 16) * 8;
        else                      srcp = A0 + (size_t)grow * 128 + c * 8;
        u32x4 v = *(const u32x4*)srcp;
        *(u32x4*)&atile[r * K + (c ^ (r & 7)) * 8] = v;
    }
    __syncthreads();

    f32x4 acc[8];
#pragma unroll
    for (int n = 0; n < 8; ++n) acc[n] = (f32x4){0.f, 0.f, 0.f, 0.f};

    int lrow = wave * 16 + fr;
#pragma unroll
    for (int ks = 0; ks < KSTEPS; ++ks) {
        int kc = ks * 4 + quad;
        bf16x8 a = *(const bf16x8*)&atile[lrow * K + (kc ^ (lrow & 7)) * 8];
#pragma unroll
        for (int n = 0; n < 8; ++n) {
            bf16x8 b = *(const bf16x8*)(Bp + ((size_t)(n * KSTEPS + ks) * 64 + lane) * 8);
            acc[n] = __builtin_amdgcn_mfma_f32_16x16x32_bf16(a, b, acc[n], 0, 0, 0);
        }
    }

    if (MODE == 0) {
        float sc[4];
#pragma unroll
        for (int j = 0; j < 4; ++j) {
            int r = row0 + quad * 4 + j;
            sc[j] = dinv[r < N_NODES ? r : N_NODES - 1];
        }
        store_tile_fp8(ctile + wave * 16 * 66, quad, fr, lane, row0, acc, sc, C8);
    } else {
        int r0 = row0 + quad * 4;
        float pr0[4] = {0.f, 0.f, 0.f, 0.f};
        float pr1[4] = {0.f, 0.f, 0.f, 0.f};
#pragma unroll
        for (int n = 0; n < 8; ++n) {
            int c = n * 16 + fr;
            float bsn = bias[c];
            float2 w = ((const float2*)Wm2)[c];
#pragma unroll
            for (int j = 0; j < 4; ++j) {
                float y = acc[n][j] + bsn;
                y = y > 0.f ? y : 0.f;
                pr0[j] = fmaf(y, w.x, pr0[j]);
                pr1[j] = fmaf(y, w.y, pr1[j]);
            }
        }
#pragma unroll
        for (int o = 1; o < 16; o <<= 1) {
#pragma unroll
            for (int j = 0; j < 4; ++j) {
                pr0[j] += __shfl_xor(pr0[j], o);
                pr1[j] += __shfl_xor(pr1[j], o);
            }
        }
        if (fr == 0) {
            float c0 = bm2[0], c1 = bm2[1];
#pragma unroll
            for (int j = 0; j < 4; ++j) {
                int r = r0 + j;
                if (r < N_NODES) {
                    out[(size_t)r * 2 + 0] = pr0[j] + c0;
                    out[(size_t)r * 2 + 1] = pr1[j] + c1;
                }
            }
        }
    }
}

// ------- fused pull-aggregate + bias + LayerNorm + ReLU (wave per node) -------
// hs8dw: [N][32] dwords of fp8 e4m3 (4 ch/dword, pre-scaled by dinv[src]).
// Wave split: eg=lane>>5 picks edge-of-pair, ch=lane&31 the row dword ->
// each 8-deep load batch covers 16 edges (one wait round per mean-degree node).
__global__ __launch_bounds__(256) void k_agg(
    const unsigned* __restrict__ hs8dw, const int* __restrict__ rowptr,
    const int* __restrict__ col, const float* __restrict__ dinv,
    const float* __restrict__ b, const float* __restrict__ g,
    const float* __restrict__ be, uint2* __restrict__ out2) {
    int wv = blockIdx.x * 4 + (threadIdx.x >> 6);
    int lane = threadIdx.x & 63;
    if (wv >= N_NODES) return;
    int eg = lane >> 5, ch = lane & 31;
    int p0 = rowptr[wv], p1 = rowptr[wv + 1];
    int ne = p1 - p0;
    float a0 = 0.f, a1 = 0.f, a2 = 0.f, a3 = 0.f;
    if (eg == 0) {                               // self-loop once
        unsigned us = hs8dw[(size_t)wv * 32 + ch];
        f32x2 w01 = __builtin_amdgcn_cvt_pk_f32_fp8(us, false);
        f32x2 w23 = __builtin_amdgcn_cvt_pk_f32_fp8(us, true);
        a0 = w01[0]; a1 = w01[1]; a2 = w23[0]; a3 = w23[1];
    }
    for (int base = 0; base < ne; base += 64) {
        int rem = ne - base;
        if (rem > 64) rem = 64;
        int myc = (lane < rem) ? col[p0 + base + lane] : -1;
        for (int j = 0; j < rem; j += 16) {      // 8 loads = 16 edges in flight
            int s0 = __shfl(myc, j + 0 + eg);
            int s1 = __shfl(myc, j + 2 + eg);
            int s2 = __shfl(myc, j + 4 + eg);
            int s3 = __shfl(myc, j + 6 + eg);
            int s4 = __shfl(myc, j + 8 + eg);
            int s5 = __shfl(myc, j + 10 + eg);
            int s6 = __shfl(myc, j + 12 + eg);
            int s7 = __shfl(myc, j + 14 + eg);
            unsigned u0 = (s0 >= 0) ? hs8dw[(size_t)s0 * 32 + ch] : 0u;
            unsigned u1 = (s1 >= 0) ? hs8dw[(size_t)s1 * 32 + ch] : 0u;
            unsigned u2 = (s2 >= 0) ? hs8dw[(size_t)s2 * 32 + ch] : 0u;
            unsigned u3 = (s3 >= 0) ? hs8dw[(size_t)s3 * 32 + ch] : 0u;
            unsigned u4 = (s4 >= 0) ? hs8dw[(size_t)s4 * 32 + ch] : 0u;
            unsigned u5 = (s5 >= 0) ? hs8dw[(size_t)s5 * 32 + ch] : 0u;
            unsigned u6 = (s6 >= 0) ? hs8dw[(size_t)s6 * 32 + ch] : 0u;
            unsigned u7 = (s7 >= 0) ? hs8dw[(size_t)s7 * 32 + ch] : 0u;
            f32x2 v;
            v = __builtin_amdgcn_cvt_pk_f32_fp8(u0, false); a0 += v[0]; a1 += v[1];
            v = __builtin_amdgcn_cvt_pk_f32_fp8(u0, true);  a2 += v[0]; a3 += v[1];
            v = __builtin_amdgcn_cvt_pk_f32_fp8(u1, false); a0 += v[0]; a1 += v[1];
            v = __builtin_amdgcn_cvt_pk_f32_fp8(u1, true);  a2 += v[0]; a3 += v[1];
            v = __builtin_amdgcn_cvt_pk_f32_fp8(u2, false); a0 += v[0]; a1 += v[1];
            v = __builtin_amdgcn_cvt_pk_f32_fp8(u2, true);  a2 += v[0]; a3 += v[1];
            v = __builtin_amdgcn_cvt_pk_f32_fp8(u3, false); a0 += v[0]; a1 += v[1];
            v = __builtin_amdgcn_cvt_pk_f32_fp8(u3, true);  a2 += v[0]; a3 += v[1];
            v = __builtin_amdgcn_cvt_pk_f32_fp8(u4, false); a0 += v[0]; a1 += v[1];
            v = __builtin_amdgcn_cvt_pk_f32_fp8(u4, true);  a2 += v[0]; a3 += v[1];
            v = __builtin_amdgcn_cvt_pk_f32_fp8(u5, false); a0 += v[0]; a1 += v[1];
            v = __builtin_amdgcn_cvt_pk_f32_fp8(u5, true);  a2 += v[0]; a3 += v[1];
            v = __builtin_amdgcn_cvt_pk_f32_fp8(u6, false); a0 += v[0]; a1 += v[1];
            v = __builtin_amdgcn_cvt_pk_f32_fp8(u6, true);  a2 += v[0]; a3 += v[1];
            v = __builtin_amdgcn_cvt_pk_f32_fp8(u7, false); a0 += v[0]; a1 += v[1];
            v = __builtin_amdgcn_cvt_pk_f32_fp8(u7, true);  a2 += v[0]; a3 += v[1];
        }
    }
    // combine the two edge groups (lane l <-> l^32)
    a0 += __shfl_xor(a0, 32);
    a1 += __shfl_xor(a1, 32);
    a2 += __shfl_xor(a2, 32);
    a3 += __shfl_xor(a3, 32);
    float dv = dinv[wv];
    float4 bb = ((const float4*)b)[ch];
    float t0 = a0 * dv + bb.x;
    float t1 = a1 * dv + bb.y;
    float t2 = a2 * dv + bb.z;
    float t3 = a3 * dv + bb.w;
    float ssum = t0 + t1 + t2 + t3;
#pragma unroll
    for (int o = 1; o < 32; o <<= 1) ssum += __shfl_xor(ssum, o);
    float mu = ssum * (1.0f / 128.0f);
    float d0 = t0 - mu, d1 = t1 - mu, d2 = t2 - mu, d3 = t3 - mu;
    float vs = d0 * d0 + d1 * d1 + d2 * d2 + d3 * d3;
#pragma unroll
    for (int o = 1; o < 32; o <<= 1) vs += __shfl_xor(vs, o);
    float rstd = rsqrtf(vs * (1.0f / 128.0f) + LN_EPS);
    if (eg == 0) {
        float4 gg = ((const float4*)g)[ch];
        float4 ee = ((const float4*)be)[ch];
        float y0 = d0 * rstd * gg.x + ee.x;
        float y1 = d1 * rstd * gg.y + ee.y;
        float y2 = d2 * rstd * gg.z + ee.z;
        float y3 = d3 * rstd * gg.w + ee.w;
        y0 = y0 > 0.f ? y0 : 0.f;
        y1 = y1 > 0.f ? y1 : 0.f;
        y2 = y2 > 0.f ? y2 : 0.f;
        y3 = y3 > 0.f ? y3 : 0.f;
        out2[(size_t)wv * 32 + ch] = make_uint2(bfpack(y0, y1), bfpack(y2, y3));
    }
}

extern "C" void kernel_launch(void* const* d_in, const int* in_sizes, int n_in,
                              void* d_out, int out_size, void* d_ws, size_t ws_size,
                              hipStream_t stream) {
    (void)in_sizes; (void)n_in; (void)out_size; (void)ws_size;
    const float* x   = (const float*)d_in[0];
    const int*   ei  = (const int*)d_in[1];
    const float* W1  = (const float*)d_in[2];
    const float* b1  = (const float*)d_in[3];
    const float* g1  = (const float*)d_in[4];
    const float* be1 = (const float*)d_in[5];
    const float* W2  = (const float*)d_in[6];
    const float* b2  = (const float*)d_in[7];
    const float* g2  = (const float*)d_in[8];
    const float* be2 = (const float*)d_in[9];
    const float* Wm1 = (const float*)d_in[10];
    const float* bm1 = (const float*)d_in[11];
    const float* Wm2 = (const float*)d_in[12];
    const float* bm2 = (const float*)d_in[13];
    const int* srcI = ei;
    const int* dstI = ei + N_EDGES;
    float* out = (float*)d_out;

    char* ws = (char*)d_ws;
    size_t off = 0;
    auto alloc = [&](size_t bytes) -> char* {
        char* p = ws + off;
        off += (bytes + 255) & ~(size_t)255;
        return p;
    };
    short* xb      = (short*)alloc((size_t)N_NODES * 128 * 2);  // x in bf16
    unsigned* bufS = (unsigned*)alloc((size_t)N_NODES * 128);   // hs1/hs2 fp8 rows
    short* bufH    = (short*)alloc((size_t)N_NODES * 128 * 2);  // h1n/h2n bf16
    short* Bp1     = (short*)alloc(128 * 128 * 2);              // fragment-packed B
    short* Bp2     = (short*)alloc(128 * 128 * 2);
    short* Bpm     = (short*)alloc(256 * 128 * 2);
    int* rowptr    = (int*)alloc((size_t)(N_NODES + 1) * 4);
    int* col       = (int*)alloc((size_t)N_EDGES * 4);
    unsigned* pairs = (unsigned*)alloc((size_t)NBUK * BCAP * 4);
    int* gcur      = (int*)alloc(NBUK * 4);
    float* dinv    = (float*)alloc((size_t)N_NODES * 4);

    hipMemsetAsync(gcur, 0, NBUK * 4, stream);

    // bucketed CSR (+ weight fragment-packing in extra blocks)
    k_bin<<<BIN_BLOCKS + 32, 256, 0, stream>>>(srcI, dstI, gcur, pairs,
                                               W1, W2, Wm1, Bp1, Bp2, Bpm);
    k_csr<<<NBUK, 256, 0, stream>>>(pairs, gcur, rowptr, dinv, col);

    int gb = (N_NODES + 63) / 64;
    int ab = (N_NODES + 3) / 4;
    // layer 1 (x convert fused into GEMM1)
    k_gemm_x<<<gb, 256, 0, stream>>>(x, Bp1, dinv, (unsigned*)xb, bufS);
    k_agg<<<ab, 256, 0, stream>>>(bufS, rowptr, col, dinv, b1, g1, be1, (uint2*)bufH);
    // layer 2
    k_gemm_mfma<0, 4><<<gb, 256, 0, stream>>>(bufH, nullptr, Bp2, dinv, nullptr,
                                              bufS, nullptr, nullptr, nullptr);
    k_agg<<<ab, 256, 0, stream>>>(bufS, rowptr, col, dinv, b2, g2, be2, (uint2*)bufH);
    // fused MLP (hidden GEMM + relu + final 128x2 + bias)
    k_gemm_mfma<1, 8><<<gb, 256, 0, stream>>>(bufH, xb, Bpm, nullptr, bm1, nullptr,
                                              Wm2, bm2, out);
}

// Round 21
// 222.825 us; speedup vs baseline: 1.0626x; 1.0211x over previous
//
#include <hip/hip_runtime.h>
#include <math.h>

#define N_NODES 100000
#define N_EDGES 1600000
#define LN_EPS 1e-5f
#define NBUK 782          // ceil(100000/128) buckets of 128 nodes
#define BCAP 2560         // bucket capacity (mean 2046, sd ~45; ~11 sigma)
#define BIN_TILE 4096     // edges per k_bin block
#define BIN_BLOCKS ((N_EDGES + BIN_TILE - 1) / BIN_TILE)   // 391

using bf16x8 = __attribute__((ext_vector_type(8))) short;
using f32x4  = __attribute__((ext_vector_type(4))) float;
using f32x2  = __attribute__((ext_vector_type(2))) float;
using u32x4  = __attribute__((ext_vector_type(4))) unsigned;

__device__ __forceinline__ unsigned short f2bf(float f) {
    unsigned u = __float_as_uint(f);
    u += 0x7fffu + ((u >> 16) & 1u);            // round-to-nearest-even
    return (unsigned short)(u >> 16);
}
__device__ __forceinline__ float bflo(unsigned u) { return __uint_as_float(u << 16); }
__device__ __forceinline__ float bfhi(unsigned u) { return __uint_as_float(u & 0xffff0000u); }
__device__ __forceinline__ unsigned bfpack(float a, float b) {
    return (unsigned)f2bf(a) | ((unsigned)f2bf(b) << 16);
}

// ------- bucketed bin pass (LDS tile cache, 512 thr); extra blocks pack B -------
// Bp[((n*KSTEPS+ks)*64 + lane)*8 + j] = bf16(W[ks*32+(lane>>4)*8+j][n*16+(lane&15)])
__global__ __launch_bounds__(512) void k_bin(
    const int* __restrict__ src, const int* __restrict__ dst,
    int* __restrict__ gcur, unsigned* __restrict__ pairs,
    const float* __restrict__ W1, const float* __restrict__ W2,
    const float* __restrict__ Wm1, short* __restrict__ Bp1,
    short* __restrict__ Bp2, short* __restrict__ Bpm) {
    int bid = blockIdx.x;
    int t = threadIdx.x;
    if (bid >= BIN_BLOCKS) {                     // weight-pack blocks
        int cid = (bid - BIN_BLOCKS) * 512 + t;  // chunk id, 8 bf16 per chunk
        if (cid >= 8192) return;
        const float* Wsrc; short* Bdst; int KST; int c;
        if (cid < 2048)      { Wsrc = W1;  Bdst = Bp1; KST = 4; c = cid; }
        else if (cid < 4096) { Wsrc = W2;  Bdst = Bp2; KST = 4; c = cid - 2048; }
        else                 { Wsrc = Wm1; Bdst = Bpm; KST = 8; c = cid - 4096; }
        int nks = c >> 6, lane = c & 63;
        int n = nks / KST, ks = nks % KST;
        int quad = lane >> 4, fr = lane & 15;
        int col0 = n * 16 + fr;
        int krow = ks * 32 + quad * 8;
        union { short s[8]; u32x4 q; } v;
#pragma unroll
        for (int j = 0; j < 8; ++j)
            v.s[j] = (short)f2bf(Wsrc[(size_t)(krow + j) * 128 + col0]);
        *(u32x4*)(Bdst + (size_t)c * 8) = v.q;
        return;
    }
    __shared__ unsigned wbuf[BIN_TILE];          // packed (d&127)<<25 | src
    __shared__ unsigned short bbuf[BIN_TILE];    // bucket id d>>7
    __shared__ int bcnt[NBUK];
    __shared__ int bbase[NBUK];
    for (int i = t; i < NBUK; i += 512) bcnt[i] = 0;
    __syncthreads();
    int e0 = bid * BIN_TILE;
    int n = N_EDGES - e0; if (n > BIN_TILE) n = BIN_TILE;
    for (int i = t; i < n; i += 512) {
        int d = __builtin_nontemporal_load(&dst[e0 + i]);
        int s = __builtin_nontemporal_load(&src[e0 + i]);
        wbuf[i] = ((unsigned)(d & 127) << 25) | (unsigned)s;
        bbuf[i] = (unsigned short)(d >> 7);
        atomicAdd(&bcnt[d >> 7], 1);
    }
    __syncthreads();
    for (int i = t; i < NBUK; i += 512) {
        int c = bcnt[i];
        bbase[i] = (c > 0) ? atomicAdd(&gcur[i], c) : 0;
        bcnt[i] = 0;
    }
    __syncthreads();
    for (int i = t; i < n; i += 512) {
        int b = bbuf[i];
        int idx = bbase[b] + atomicAdd(&bcnt[b], 1);
        if (idx < BCAP)
            pairs[(size_t)b * BCAP + idx] = wbuf[i];
    }
}

// per-bucket local CSR (computes own prefix base)
__global__ __launch_bounds__(256) void k_csr(
    const unsigned* __restrict__ pairs, const int* __restrict__ gcur,
    int* __restrict__ rowptr, float* __restrict__ dinv, int* __restrict__ col) {
    int b = blockIdx.x;
    int t = threadIdx.x;
    int lane = t & 63, wid = t >> 6;
    __shared__ int redsum[4];
    int part = 0;
    for (int i = t; i < b; i += 256) part += gcur[i];
#pragma unroll
    for (int o = 32; o; o >>= 1) part += __shfl_xor(part, o);
    if (lane == 0) redsum[wid] = part;
    __syncthreads();
    int base = redsum[0] + redsum[1] + redsum[2] + redsum[3];
    if (b == 0 && t == 0) rowptr[N_NODES] = N_EDGES;

    int lo = b << 7;
    int nloc = N_NODES - lo; if (nloc > 128) nloc = 128;
    int size = gcur[b]; if (size > BCAP) size = BCAP;
    __shared__ int lcnt[128], lofs[128], lcur[128];
    if (t < 128) lcnt[t] = 0;
    __syncthreads();
    const unsigned* bp = pairs + (size_t)b * BCAP;
    for (int i = t; i < size; i += 256) atomicAdd(&lcnt[bp[i] >> 25], 1);
    __syncthreads();
    if (t < 128) lofs[t] = lcnt[t];
    __syncthreads();
    for (int o = 1; o < 128; o <<= 1) {
        int v = 0;
        if (t < 128 && t >= o) v = lofs[t - o];
        __syncthreads();
        if (t < 128) lofs[t] += v;
        __syncthreads();
    }
    if (t < 128) {
        int ex = lofs[t] - lcnt[t];               // exclusive
        if (t < nloc) {
            rowptr[lo + t] = base + ex;
            dinv[lo + t] = rsqrtf((float)(lcnt[t] + 1));
        }
        lcur[t] = ex;
    }
    __syncthreads();
    for (int i = t; i < size; i += 256) {
        unsigned w = bp[i];
        int pos = atomicAdd(&lcur[w >> 25], 1);
        col[base + pos] = (int)(w & 0x1FFFFFFu);
    }
}

// --- coalesced fp8 C-store: stage bf16 tile in LDS, convert on readback ---
__device__ __forceinline__ void store_tile_fp8(
    unsigned* wtile, int quad, int fr, int lane, int row0w,
    const f32x4* acc, const float* scale4, unsigned* C8) {
    unsigned short* w16 = (unsigned short*)wtile;
#pragma unroll
    for (int j = 0; j < 4; ++j) {
        float s = scale4[j];
#pragma unroll
        for (int n = 0; n < 8; ++n)
            w16[(quad * 4 + j) * 132 + n * 16 + fr] = f2bf(acc[n][j] * s);
    }
    __builtin_amdgcn_s_waitcnt(0);               // drain lgkm before cross-lane read
    int lrow = lane >> 2, chk = lane & 3;
    int gr = row0w + lrow;
    if (gr < N_NODES) {
#pragma unroll
        for (int q = 0; q < 4; ++q) {
            u32x4 v = *(u32x4*)&wtile[lrow * 66 + chk * 16 + q * 4];
            int d0 = __builtin_amdgcn_cvt_pk_fp8_f32(bflo(v[0]), bfhi(v[0]), 0, false);
            d0 = __builtin_amdgcn_cvt_pk_fp8_f32(bflo(v[1]), bfhi(v[1]), d0, true);
            int d1 = __builtin_amdgcn_cvt_pk_fp8_f32(bflo(v[2]), bfhi(v[2]), 0, false);
            d1 = __builtin_amdgcn_cvt_pk_fp8_f32(bflo(v[3]), bfhi(v[3]), d1, true);
            uint2 dd = make_uint2((unsigned)d0, (unsigned)d1);
            *(uint2*)(C8 + (size_t)gr * 32 + chk * 8 + q * 2) = dd;
        }
    }
}

// ------------- GEMM1: hs1 = fp8((x@W1)*dinv), also emits xb = bf16(x) -------------
__global__ __launch_bounds__(256) void k_gemm_x(
    const float* __restrict__ x, const short* __restrict__ Bp1,
    const float* __restrict__ dinv, unsigned* __restrict__ xbu,
    unsigned* __restrict__ hs1u8) {
    __shared__ unsigned ctile[4][16 * 66];
    int t = threadIdx.x;
    int wave = t >> 6, lane = t & 63;
    int quad = lane >> 4, fr = lane & 15;
    int row0 = blockIdx.x * 64 + wave * 16;
    int arow = row0 + fr;
    if (arow >= N_NODES) arow = N_NODES - 1;

    f32x4 acc[8];
#pragma unroll
    for (int n = 0; n < 8; ++n) acc[n] = (f32x4){0.f, 0.f, 0.f, 0.f};

#pragma unroll
    for (int ks = 0; ks < 4; ++ks) {
        int kof = ks * 32 + quad * 8;            // shorts
        const f32x4* xr = (const f32x4*)(x + (size_t)arow * 128 + kof);
        f32x4 v0 = __builtin_nontemporal_load(&xr[0]);
        f32x4 v1 = __builtin_nontemporal_load(&xr[1]);
        union { unsigned u[4]; bf16x8 v; u32x4 q; } cv;
        cv.u[0] = bfpack(v0[0], v0[1]);
        cv.u[1] = bfpack(v0[2], v0[3]);
        cv.u[2] = bfpack(v1[0], v1[1]);
        cv.u[3] = bfpack(v1[2], v1[3]);
        *(u32x4*)(xbu + (size_t)arow * 64 + ks * 16 + quad * 4) = cv.q;
#pragma unroll
        for (int n = 0; n < 8; ++n) {
            bf16x8 b = *(const bf16x8*)(Bp1 + ((size_t)(n * 4 + ks) * 64 + lane) * 8);
            acc[n] = __builtin_amdgcn_mfma_f32_16x16x32_bf16(cv.v, b, acc[n], 0, 0, 0);
        }
    }
    float sc[4];
#pragma unroll
    for (int j = 0; j < 4; ++j) {
        int r = row0 + quad * 4 + j;
        sc[j] = dinv[r < N_NODES ? r : N_NODES - 1];
    }
    store_tile_fp8(ctile[wave], quad, fr, lane, row0, acc, sc, hs1u8);
}

// ------------- bf16 MFMA GEMM: LDS-staged A + fragment-packed B -------------
// MODE 0: epilogue *dinv[row], fp8 C via LDS tile.
// MODE 1: A=concat(A0,A1) (K=256); epilogue relu(.+bias) @ Wm2 + bm2 -> out[N,2]
template <int MODE, int KSTEPS>
__global__ __launch_bounds__(256) void k_gemm_mfma(
    const short* __restrict__ A0, const short* __restrict__ A1,
    const short* __restrict__ Bp, const float* __restrict__ dinv,
    const float* __restrict__ bias, unsigned* __restrict__ C8,
    const float* __restrict__ Wm2, const float* __restrict__ bm2,
    float* __restrict__ out) {
    constexpr int K = KSTEPS * 32;               // 128 or 256
    constexpr int CHUNKS = K / 8;                // 16B chunks per row
    __shared__ short atile[64 * K];
    __shared__ unsigned ctile[MODE == 0 ? 4 * 16 * 66 : 4];
    int t = threadIdx.x;
    int wave = t >> 6, lane = t & 63;
    int quad = lane >> 4, fr = lane & 15;
    int row0 = blockIdx.x * 64 + wave * 16;

    // ---- stage A tile (64 rows x K) into swizzled LDS ----
#pragma unroll
    for (int i = 0; i < (64 * CHUNKS) / 256; ++i) {
        int idx = i * 256 + t;
        int r = idx / CHUNKS;
        int c = idx % CHUNKS;
        int grow = blockIdx.x * 64 + r;
        if (grow >= N_NODES) grow = N_NODES - 1;
        const short* srcp;
        if (MODE == 1 && c >= 16) srcp = A1 + (size_t)grow * 128 + (c - 16) * 8;
        else                      srcp = A0 + (size_t)grow * 128 + c * 8;
        u32x4 v = *(const u32x4*)srcp;
        *(u32x4*)&atile[r * K + (c ^ (r & 7)) * 8] = v;
    }
    __syncthreads();

    f32x4 acc[8];
#pragma unroll
    for (int n = 0; n < 8; ++n) acc[n] = (f32x4){0.f, 0.f, 0.f, 0.f};

    int lrow = wave * 16 + fr;
#pragma unroll
    for (int ks = 0; ks < KSTEPS; ++ks) {
        int kc = ks * 4 + quad;
        bf16x8 a = *(const bf16x8*)&atile[lrow * K + (kc ^ (lrow & 7)) * 8];
#pragma unroll
        for (int n = 0; n < 8; ++n) {
            bf16x8 b = *(const bf16x8*)(Bp + ((size_t)(n * KSTEPS + ks) * 64 + lane) * 8);
            acc[n] = __builtin_amdgcn_mfma_f32_16x16x32_bf16(a, b, acc[n], 0, 0, 0);
        }
    }

    if (MODE == 0) {
        float sc[4];
#pragma unroll
        for (int j = 0; j < 4; ++j) {
            int r = row0 + quad * 4 + j;
            sc[j] = dinv[r < N_NODES ? r : N_NODES - 1];
        }
        store_tile_fp8(ctile + wave * 16 * 66, quad, fr, lane, row0, acc, sc, C8);
    } else {
        int r0 = row0 + quad * 4;
        float pr0[4] = {0.f, 0.f, 0.f, 0.f};
        float pr1[4] = {0.f, 0.f, 0.f, 0.f};
#pragma unroll
        for (int n = 0; n < 8; ++n) {
            int c = n * 16 + fr;
            float bsn = bias[c];
            float2 w = ((const float2*)Wm2)[c];
#pragma unroll
            for (int j = 0; j < 4; ++j) {
                float y = acc[n][j] + bsn;
                y = y > 0.f ? y : 0.f;
                pr0[j] = fmaf(y, w.x, pr0[j]);
                pr1[j] = fmaf(y, w.y, pr1[j]);
            }
        }
#pragma unroll
        for (int o = 1; o < 16; o <<= 1) {
#pragma unroll
            for (int j = 0; j < 4; ++j) {
                pr0[j] += __shfl_xor(pr0[j], o);
                pr1[j] += __shfl_xor(pr1[j], o);
            }
        }
        if (fr == 0) {
            float c0 = bm2[0], c1 = bm2[1];
#pragma unroll
            for (int j = 0; j < 4; ++j) {
                int r = r0 + j;
                if (r < N_NODES) {
                    out[(size_t)r * 2 + 0] = pr0[j] + c0;
                    out[(size_t)r * 2 + 1] = pr1[j] + c1;
                }
            }
        }
    }
}

// ------- fused pull-aggregate + bias + LayerNorm + ReLU (wave per node) -------
// hs8dw: [N][32] dwords of fp8 e4m3 (4 ch/dword, pre-scaled by dinv[src]).
// Wave split: eg=lane>>5 edge-of-pair, ch=lane&31 row dword; 16 edges in flight.
// Packed f32x2 accumulators -> v_pk_add_f32 (halves the add count).
__global__ __launch_bounds__(256) void k_agg(
    const unsigned* __restrict__ hs8dw, const int* __restrict__ rowptr,
    const int* __restrict__ col, const float* __restrict__ dinv,
    const float* __restrict__ b, const float* __restrict__ g,
    const float* __restrict__ be, uint2* __restrict__ out2) {
    int wv = blockIdx.x * 4 + (threadIdx.x >> 6);
    int lane = threadIdx.x & 63;
    if (wv >= N_NODES) return;
    int eg = lane >> 5, ch = lane & 31;
    int p0 = rowptr[wv], p1 = rowptr[wv + 1];
    int ne = p1 - p0;
    f32x2 acc01 = (f32x2){0.f, 0.f}, acc23 = (f32x2){0.f, 0.f};
    if (eg == 0) {                               // self-loop once
        unsigned us = hs8dw[(size_t)wv * 32 + ch];
        acc01 = __builtin_amdgcn_cvt_pk_f32_fp8(us, false);
        acc23 = __builtin_amdgcn_cvt_pk_f32_fp8(us, true);
    }
    for (int base = 0; base < ne; base += 64) {
        int rem = ne - base;
        if (rem > 64) rem = 64;
        int myc = (lane < rem) ? col[p0 + base + lane] : -1;
        for (int j = 0; j < rem; j += 16) {      // 8 loads = 16 edges in flight
            int s0 = __shfl(myc, j + 0 + eg);
            int s1 = __shfl(myc, j + 2 + eg);
            int s2 = __shfl(myc, j + 4 + eg);
            int s3 = __shfl(myc, j + 6 + eg);
            int s4 = __shfl(myc, j + 8 + eg);
            int s5 = __shfl(myc, j + 10 + eg);
            int s6 = __shfl(myc, j + 12 + eg);
            int s7 = __shfl(myc, j + 14 + eg);
            unsigned u0 = (s0 >= 0) ? hs8dw[(size_t)s0 * 32 + ch] : 0u;
            unsigned u1 = (s1 >= 0) ? hs8dw[(size_t)s1 * 32 + ch] : 0u;
            unsigned u2 = (s2 >= 0) ? hs8dw[(size_t)s2 * 32 + ch] : 0u;
            unsigned u3 = (s3 >= 0) ? hs8dw[(size_t)s3 * 32 + ch] : 0u;
            unsigned u4 = (s4 >= 0) ? hs8dw[(size_t)s4 * 32 + ch] : 0u;
            unsigned u5 = (s5 >= 0) ? hs8dw[(size_t)s5 * 32 + ch] : 0u;
            unsigned u6 = (s6 >= 0) ? hs8dw[(size_t)s6 * 32 + ch] : 0u;
            unsigned u7 = (s7 >= 0) ? hs8dw[(size_t)s7 * 32 + ch] : 0u;
            acc01 += __builtin_amdgcn_cvt_pk_f32_fp8(u0, false);
            acc23 += __builtin_amdgcn_cvt_pk_f32_fp8(u0, true);
            acc01 += __builtin_amdgcn_cvt_pk_f32_fp8(u1, false);
            acc23 += __builtin_amdgcn_cvt_pk_f32_fp8(u1, true);
            acc01 += __builtin_amdgcn_cvt_pk_f32_fp8(u2, false);
            acc23 += __builtin_amdgcn_cvt_pk_f32_fp8(u2, true);
            acc01 += __builtin_amdgcn_cvt_pk_f32_fp8(u3, false);
            acc23 += __builtin_amdgcn_cvt_pk_f32_fp8(u3, true);
            acc01 += __builtin_amdgcn_cvt_pk_f32_fp8(u4, false);
            acc23 += __builtin_amdgcn_cvt_pk_f32_fp8(u4, true);
            acc01 += __builtin_amdgcn_cvt_pk_f32_fp8(u5, false);
            acc23 += __builtin_amdgcn_cvt_pk_f32_fp8(u5, true);
            acc01 += __builtin_amdgcn_cvt_pk_f32_fp8(u6, false);
            acc23 += __builtin_amdgcn_cvt_pk_f32_fp8(u6, true);
            acc01 += __builtin_amdgcn_cvt_pk_f32_fp8(u7, false);
            acc23 += __builtin_amdgcn_cvt_pk_f32_fp8(u7, true);
        }
    }
    float a0 = acc01[0], a1 = acc01[1], a2 = acc23[0], a3 = acc23[1];
    // combine the two edge groups (lane l <-> l^32)
    a0 += __shfl_xor(a0, 32);
    a1 += __shfl_xor(a1, 32);
    a2 += __shfl_xor(a2, 32);
    a3 += __shfl_xor(a3, 32);
    float dv = dinv[wv];
    float4 bb = ((const float4*)b)[ch];
    float t0 = a0 * dv + bb.x;
    float t1 = a1 * dv + bb.y;
    float t2 = a2 * dv + bb.z;
    float t3 = a3 * dv + bb.w;
    float ssum = t0 + t1 + t2 + t3;
#pragma unroll
    for (int o = 1; o < 32; o <<= 1) ssum += __shfl_xor(ssum, o);
    float mu = ssum * (1.0f / 128.0f);
    float d0 = t0 - mu, d1 = t1 - mu, d2 = t2 - mu, d3 = t3 - mu;
    float vs = d0 * d0 + d1 * d1 + d2 * d2 + d3 * d3;
#pragma unroll
    for (int o = 1; o < 32; o <<= 1) vs += __shfl_xor(vs, o);
    float rstd = rsqrtf(vs * (1.0f / 128.0f) + LN_EPS);
    if (eg == 0) {
        float4 gg = ((const float4*)g)[ch];
        float4 ee = ((const float4*)be)[ch];
        float y0 = d0 * rstd * gg.x + ee.x;
        float y1 = d1 * rstd * gg.y + ee.y;
        float y2 = d2 * rstd * gg.z + ee.z;
        float y3 = d3 * rstd * gg.w + ee.w;
        y0 = y0 > 0.f ? y0 : 0.f;
        y1 = y1 > 0.f ? y1 : 0.f;
        y2 = y2 > 0.f ? y2 : 0.f;
        y3 = y3 > 0.f ? y3 : 0.f;
        out2[(size_t)wv * 32 + ch] = make_uint2(bfpack(y0, y1), bfpack(y2, y3));
    }
}

extern "C" void kernel_launch(void* const* d_in, const int* in_sizes, int n_in,
                              void* d_out, int out_size, void* d_ws, size_t ws_size,
                              hipStream_t stream) {
    (void)in_sizes; (void)n_in; (void)out_size; (void)ws_size;
    const float* x   = (const float*)d_in[0];
    const int*   ei  = (const int*)d_in[1];
    const float* W1  = (const float*)d_in[2];
    const float* b1  = (const float*)d_in[3];
    const float* g1  = (const float*)d_in[4];
    const float* be1 = (const float*)d_in[5];
    const float* W2  = (const float*)d_in[6];
    const float* b2  = (const float*)d_in[7];
    const float* g2  = (const float*)d_in[8];
    const float* be2 = (const float*)d_in[9];
    const float* Wm1 = (const float*)d_in[10];
    const float* bm1 = (const float*)d_in[11];
    const float* Wm2 = (const float*)d_in[12];
    const float* bm2 = (const float*)d_in[13];
    const int* srcI = ei;
    const int* dstI = ei + N_EDGES;
    float* out = (float*)d_out;

    char* ws = (char*)d_ws;
    size_t off = 0;
    auto alloc = [&](size_t bytes) -> char* {
        char* p = ws + off;
        off += (bytes + 255) & ~(size_t)255;
        return p;
    };
    short* xb      = (short*)alloc((size_t)N_NODES * 128 * 2);  // x in bf16
    unsigned* bufS = (unsigned*)alloc((size_t)N_NODES * 128);   // hs1/hs2 fp8 rows
    short* bufH    = (short*)alloc((size_t)N_NODES * 128 * 2);  // h1n/h2n bf16
    short* Bp1     = (short*)alloc(128 * 128 * 2);              // fragment-packed B
    short* Bp2     = (short*)alloc(128 * 128 * 2);
    short* Bpm     = (short*)alloc(256 * 128 * 2);
    int* rowptr    = (int*)alloc((size_t)(N_NODES + 1) * 4);
    int* col       = (int*)alloc((size_t)N_EDGES * 4);
    unsigned* pairs = (unsigned*)alloc((size_t)NBUK * BCAP * 4);
    int* gcur      = (int*)alloc(NBUK * 4);
    float* dinv    = (float*)alloc((size_t)N_NODES * 4);

    hipMemsetAsync(gcur, 0, NBUK * 4, stream);

    // bucketed CSR (+ weight fragment-packing in extra blocks)
    k_bin<<<BIN_BLOCKS + 16, 512, 0, stream>>>(srcI, dstI, gcur, pairs,
                                               W1, W2, Wm1, Bp1, Bp2, Bpm);
    k_csr<<<NBUK, 256, 0, stream>>>(pairs, gcur, rowptr, dinv, col);

    int gb = (N_NODES + 63) / 64;
    int ab = (N_NODES + 3) / 4;
    // layer 1 (x convert fused into GEMM1)
    k_gemm_x<<<gb, 256, 0, stream>>>(x, Bp1, dinv, (unsigned*)xb, bufS);
    k_agg<<<ab, 256, 0, stream>>>(bufS, rowptr, col, dinv, b1, g1, be1, (uint2*)bufH);
    // layer 2
    k_gemm_mfma<0, 4><<<gb, 256, 0, stream>>>(bufH, nullptr, Bp2, dinv, nullptr,
                                              bufS, nullptr, nullptr, nullptr);
    k_agg<<<ab, 256, 0, stream>>>(bufS, rowptr, col, dinv, b2, g2, be2, (uint2*)bufH);
    // fused MLP (hidden GEMM + relu + final 128x2 + bias)
    k_gemm_mfma<1, 8><<<gb, 256, 0, stream>>>(bufH, xb, Bpm, nullptr, bm1, nullptr,
                                              Wm2, bm2, out);
}